// Round 1
// baseline (340.489 us; speedup 1.0000x reference)
//
#include <hip/hip_runtime.h>
#include <hip/hip_bf16.h>

// Problem constants
#define B_   4
#define S_   2048
#define H_   1024
#define NH_  16
#define HD_  64
#define M_   8192   // B_*S_
#define K_   1024

using bf16x8 = __bf16 __attribute__((ext_vector_type(8)));
using f32x4  = float __attribute__((ext_vector_type(4)));

__device__ inline f32x4 mfma16(bf16x8 a, bf16x8 b, f32x4 c) {
    return __builtin_amdgcn_mfma_f32_16x16x32_bf16(a, b, c, 0, 0, 0);
}

__device__ inline unsigned short f2bf(float f) {
    __hip_bfloat16 h = __float2bfloat16(f);
    return *reinterpret_cast<unsigned short*>(&h);
}

// ---------------------------------------------------------------------------
// Workspace layout (elements of ushort unless noted):
//   xb   @ 0          (M*K)      bf16 x            [also reused as attn-out]
//   wqb  @ 8388608    (1M)
//   wkb  @ 9437184
//   wvb  @ 10485760
//   wob  @ 11534336
//   qbuf @ 12582912   (B,NH,S,HD) bf16, RoPE'd, pre-scaled by 1/8
//   kbuf @ 20971520   (B,NH,S,HD) bf16, RoPE'd
//   vtbuf@ 29360128   (B,NH,HD,S) bf16 (transposed V)
//   cos  @ 37748736 (float, 65536) ; sin follows
// total = 76,021,760 bytes
// ---------------------------------------------------------------------------

// fp32 -> bf16 conversion for x and the 4 weight matrices (float4 vectorized)
__global__ __launch_bounds__(256) void prep_convert(
    const float* __restrict__ x,  const float* __restrict__ wq,
    const float* __restrict__ wk, const float* __restrict__ wv,
    const float* __restrict__ wo, unsigned short* __restrict__ ws)
{
    size_t u = (size_t)blockIdx.x * 256 + threadIdx.x;   // 3,145,728 units of 4 floats
    const float* src; unsigned short* dst; size_t off;
    if (u < 2097152)      { src = x;  dst = ws;            off = u * 4; }
    else if (u < 2359296) { src = wq; dst = ws + 8388608;  off = (u - 2097152) * 4; }
    else if (u < 2621440) { src = wk; dst = ws + 9437184;  off = (u - 2359296) * 4; }
    else if (u < 2883584) { src = wv; dst = ws + 10485760; off = (u - 2621440) * 4; }
    else                  { src = wo; dst = ws + 11534336; off = (u - 2883584) * 4; }
    float4 v = *reinterpret_cast<const float4*>(src + off);
    ushort4 o;
    o.x = f2bf(v.x); o.y = f2bf(v.y); o.z = f2bf(v.z); o.w = f2bf(v.w);
    *reinterpret_cast<ushort4*>(dst + off) = o;
}

// cos/sin tables: [S][32] each
__global__ __launch_bounds__(256) void rope_table(float* __restrict__ cosb,
                                                  float* __restrict__ sinb)
{
    int idx = blockIdx.x * 256 + threadIdx.x;   // 65536
    int pos = idx >> 5, i = idx & 31;
    // inv = 10000^(-(2i)/64)
    float inv = expf(-(float)(2 * i) * (9.210340371976184f / 64.0f));
    float ang = (float)pos * inv;
    cosb[idx] = cosf(ang);
    sinb[idx] = sinf(ang);
}

// ---------------------------------------------------------------------------
// GEMM: C[M x 1024] = A[M x 1024] * W^T   (W stored row-major [1024 x 1024])
// 128x128 block tile, 4 waves of 64x64, BK=64, XOR-swizzled LDS.
// EPI 0: RoPE + scale -> bf16 (B,NH,S,HD)
// EPI 1: transposed V -> bf16 (B,NH,HD,S)
// EPI 2: fp32 -> out (B,S,H)
// ---------------------------------------------------------------------------
template<int EPI>
__global__ __launch_bounds__(256) void gemm_bt(
    const unsigned short* __restrict__ A,
    const unsigned short* __restrict__ W,
    void* __restrict__ outp,
    const float* __restrict__ cosb, const float* __restrict__ sinb,
    float scale)
{
    __shared__ alignas(16) unsigned short Al[128 * 64];
    __shared__ alignas(16) unsigned short Bl[128 * 64];

    const int t = threadIdx.x;
    const int l = t & 63;
    const int w = t >> 6;
    const int lane_r = l & 15, lane_g = l >> 4;
    const int bn = blockIdx.x, bm = blockIdx.y;
    const size_t rowbase = (size_t)bm * 128;
    const int colbase = bn * 128;
    const int wm = (w >> 1) * 64, wn = (w & 1) * 64;
    const int r0 = t >> 3, c8 = t & 7;

    f32x4 zero4 = {0.f, 0.f, 0.f, 0.f};
    f32x4 acc[4][4];
#pragma unroll
    for (int a = 0; a < 4; a++)
#pragma unroll
        for (int b2 = 0; b2 < 4; b2++) acc[a][b2] = zero4;

    for (int k0 = 0; k0 < K_; k0 += 64) {
        bf16x8 ra[4], rb[4];
#pragma unroll
        for (int i = 0; i < 4; i++) {
            int row = i * 32 + r0;
            ra[i] = *reinterpret_cast<const bf16x8*>(A + (rowbase + row) * K_ + k0 + c8 * 8);
            rb[i] = *reinterpret_cast<const bf16x8*>(W + (size_t)(colbase + row) * K_ + k0 + c8 * 8);
        }
        __syncthreads();
#pragma unroll
        for (int i = 0; i < 4; i++) {
            int row = i * 32 + r0;
            int off = (row * 128 + c8 * 16) ^ ((row & 7) << 4);
            *reinterpret_cast<bf16x8*>((char*)Al + off) = ra[i];
            *reinterpret_cast<bf16x8*>((char*)Bl + off) = rb[i];
        }
        __syncthreads();

        bf16x8 af[4][2], bfr[4][2];
#pragma unroll
        for (int mt = 0; mt < 4; mt++)
#pragma unroll
            for (int kk = 0; kk < 2; kk++) {
                int rowa = wm + mt * 16 + lane_r;
                int offa = (rowa * 128 + kk * 64 + lane_g * 16) ^ ((rowa & 7) << 4);
                af[mt][kk] = *reinterpret_cast<const bf16x8*>((const char*)Al + offa);
                int rowb = wn + mt * 16 + lane_r;
                int offb = (rowb * 128 + kk * 64 + lane_g * 16) ^ ((rowb & 7) << 4);
                bfr[mt][kk] = *reinterpret_cast<const bf16x8*>((const char*)Bl + offb);
            }
#pragma unroll
        for (int mt = 0; mt < 4; mt++)
#pragma unroll
            for (int nt = 0; nt < 4; nt++) {
                acc[mt][nt] = mfma16(af[mt][0], bfr[nt][0], acc[mt][nt]);
                acc[mt][nt] = mfma16(af[mt][1], bfr[nt][1], acc[mt][nt]);
            }
    }

    // Epilogue.  D-layout: row = (l>>4)*4 + i, col = l&15 within each 16x16.
#pragma unroll
    for (int mt = 0; mt < 4; mt++) {
#pragma unroll
        for (int nt = 0; nt < 4; nt++) {
            if constexpr (EPI == 2) {
                float* out = (float*)outp;
#pragma unroll
                for (int i = 0; i < 4; i++) {
                    size_t r = rowbase + wm + mt * 16 + lane_g * 4 + i;
                    int n = colbase + wn + nt * 16 + lane_r;
                    out[r * 1024 + n] = acc[mt][nt][i];
                }
            } else if constexpr (EPI == 0) {
                unsigned short* out = (unsigned short*)outp;
#pragma unroll
                for (int i = 0; i < 4; i++) {
                    size_t r = rowbase + wm + mt * 16 + lane_g * 4 + i;
                    int n = colbase + wn + nt * 16 + lane_r;
                    int b   = (int)(r >> 11);
                    int pos = (int)(r & 2047);
                    int h = n >> 6, d = n & 63;
                    float cv = cosb[pos * 32 + (d >> 1)];
                    float sv = sinb[pos * 32 + (d >> 1)];
                    float val = acc[mt][nt][i];
                    float partner = __shfl_xor(val, 1);
                    // even d: x0*c - x1*s ; odd d: x0*s + x1*c
                    float o = (d & 1) ? (partner * sv + val * cv)
                                      : (val * cv - partner * sv);
                    o *= scale;
                    out[(((size_t)(b * NH_ + h)) * S_ + pos) * 64 + d] = f2bf(o);
                }
            } else { // EPI == 1 : transposed V
                unsigned short* out = (unsigned short*)outp;
                size_t rr = rowbase + wm + mt * 16 + lane_g * 4;
                int n = colbase + wn + nt * 16 + lane_r;
                int b   = (int)(rr >> 11);
                int pos = (int)(rr & 2047);
                int h = n >> 6, d = n & 63;
                ushort4 o;
                o.x = f2bf(acc[mt][nt][0]); o.y = f2bf(acc[mt][nt][1]);
                o.z = f2bf(acc[mt][nt][2]); o.w = f2bf(acc[mt][nt][3]);
                *reinterpret_cast<ushort4*>(
                    out + (((size_t)(b * NH_ + h)) * 64 + d) * S_ + pos) = o;
            }
        }
    }
}

// ---------------------------------------------------------------------------
// Flash attention: one (b,h) x 64 q-rows per block, 4 waves x 16 rows.
// K-tiles of 64 keys, online softmax, P via per-wave swizzled LDS.
// ---------------------------------------------------------------------------
__global__ __launch_bounds__(256) void attn_fwd(
    const unsigned short* __restrict__ qb, const unsigned short* __restrict__ kb,
    const unsigned short* __restrict__ vt, const int* __restrict__ mask,
    unsigned short* __restrict__ ao)
{
    __shared__ alignas(16) unsigned short Kl[64 * 64];
    __shared__ alignas(16) unsigned short Vl[64 * 64];
    __shared__ alignas(16) unsigned short Pl[4][16 * 64];
    __shared__ int Ml[S_];

    // XCD-clustering swizzle: all 32 q-tiles of a (b,h) land on one XCD.
    const int bid = blockIdx.x;
    const int xcd = bid & 7, idx = bid >> 3;
    const int bh = xcd * 8 + (idx >> 5);
    const int qt = idx & 31;
    const int b = bh >> 4, h = bh & 15;

    const int t = threadIdx.x, l = t & 63, w = t >> 6;
    const int lane_r = l & 15, lane_g = l >> 4;
    const int r0 = t >> 3, c8 = t & 7;

    const unsigned short* qp = qb + (size_t)bh * S_ * 64;
    const unsigned short* kp = kb + (size_t)bh * S_ * 64;
    const unsigned short* vp = vt + (size_t)bh * 64 * S_;

    {   // mask row for this batch -> LDS
        const int4* msrc = reinterpret_cast<const int4*>(mask + (size_t)b * S_);
        int4* mdst = reinterpret_cast<int4*>(Ml);
        for (int i = t; i < S_ / 4; i += 256) mdst[i] = msrc[i];
    }

    // Q fragments (q pre-scaled by 1/8 in projection epilogue)
    bf16x8 qf[2];
    {
        int qrow = qt * 64 + w * 16 + lane_r;
        qf[0] = *reinterpret_cast<const bf16x8*>(qp + (size_t)qrow * 64 + lane_g * 8);
        qf[1] = *reinterpret_cast<const bf16x8*>(qp + (size_t)qrow * 64 + 32 + lane_g * 8);
    }

    f32x4 zero4 = {0.f, 0.f, 0.f, 0.f};
    float m_run[4], l_run[4];
    f32x4 oacc[4];
#pragma unroll
    for (int i = 0; i < 4; i++) { m_run[i] = -3.0e38f; l_run[i] = 0.f; oacc[i] = zero4; }

    for (int kt = 0; kt < 32; kt++) {
        // stage K tile [64 keys][64 d] and Vt tile [64 d][64 keys]
        bf16x8 rk[2], rv[2];
#pragma unroll
        for (int i = 0; i < 2; i++) {
            int row = i * 32 + r0;
            rk[i] = *reinterpret_cast<const bf16x8*>(kp + (size_t)(kt * 64 + row) * 64 + c8 * 8);
            rv[i] = *reinterpret_cast<const bf16x8*>(vp + (size_t)row * S_ + kt * 64 + c8 * 8);
        }
        __syncthreads();
#pragma unroll
        for (int i = 0; i < 2; i++) {
            int row = i * 32 + r0;
            int off = (row * 128 + c8 * 16) ^ ((row & 7) << 4);
            *reinterpret_cast<bf16x8*>((char*)Kl + off) = rk[i];
            *reinterpret_cast<bf16x8*>((char*)Vl + off) = rv[i];
        }
        __syncthreads();

        // QK^T: s[nt] cols nt*16+lane_r, rows lane_g*4+i
        f32x4 s[4];
#pragma unroll
        for (int nt = 0; nt < 4; nt++) {
            int row = nt * 16 + lane_r;
            int off0 = (row * 128 + lane_g * 16) ^ ((row & 7) << 4);
            bf16x8 k0v = *reinterpret_cast<const bf16x8*>((const char*)Kl + off0);
            bf16x8 k1v = *reinterpret_cast<const bf16x8*>((const char*)Kl + (off0 ^ 64));
            s[nt] = mfma16(qf[0], k0v, zero4);
            s[nt] = mfma16(qf[1], k1v, s[nt]);
        }
        // key mask
#pragma unroll
        for (int nt = 0; nt < 4; nt++) {
            int mk = Ml[kt * 64 + nt * 16 + lane_r];
            if (mk == 0) { s[nt][0] = -3e38f; s[nt][1] = -3e38f; s[nt][2] = -3e38f; s[nt][3] = -3e38f; }
        }
        // row max (across 4 nt locally + 16-lane butterfly)
        float sc[4];
#pragma unroll
        for (int i = 0; i < 4; i++) {
            float v = fmaxf(fmaxf(s[0][i], s[1][i]), fmaxf(s[2][i], s[3][i]));
            v = fmaxf(v, __shfl_xor(v, 1));
            v = fmaxf(v, __shfl_xor(v, 2));
            v = fmaxf(v, __shfl_xor(v, 4));
            v = fmaxf(v, __shfl_xor(v, 8));
            float mn = fmaxf(m_run[i], v);
            sc[i] = __expf(m_run[i] - mn);
            m_run[i] = mn;
        }
        // p = exp(s - m), row sums
        float rs[4] = {0.f, 0.f, 0.f, 0.f};
        f32x4 p[4];
#pragma unroll
        for (int nt = 0; nt < 4; nt++)
#pragma unroll
            for (int i = 0; i < 4; i++) {
                float pv = __expf(s[nt][i] - m_run[i]);
                p[nt][i] = pv;
                rs[i] += pv;
            }
#pragma unroll
        for (int i = 0; i < 4; i++) {
            float v = rs[i];
            v += __shfl_xor(v, 1); v += __shfl_xor(v, 2);
            v += __shfl_xor(v, 4); v += __shfl_xor(v, 8);
            l_run[i] = l_run[i] * sc[i] + v;
        }
#pragma unroll
        for (int nt = 0; nt < 4; nt++)
#pragma unroll
            for (int i = 0; i < 4; i++) oacc[nt][i] *= sc[i];

        // P (D-layout) -> per-wave LDS (A-layout readable)
        unsigned short* pl = (unsigned short*)Pl[w];
#pragma unroll
        for (int nt = 0; nt < 4; nt++)
#pragma unroll
            for (int i = 0; i < 4; i++) {
                int row = lane_g * 4 + i;
                int off = (row * 128 + (nt * 16 + lane_r) * 2) ^ ((row & 7) << 4);
                *reinterpret_cast<unsigned short*>((char*)pl + off) = f2bf(p[nt][i]);
            }
        asm volatile("" ::: "memory");   // keep compiler from reordering LDS ops

        // PV
        bf16x8 pa0 = *reinterpret_cast<const bf16x8*>(
            (const char*)pl + ((lane_r * 128 + lane_g * 16) ^ ((lane_r & 7) << 4)));
        bf16x8 pa1 = *reinterpret_cast<const bf16x8*>(
            (const char*)pl + ((lane_r * 128 + 64 + lane_g * 16) ^ ((lane_r & 7) << 4)));
#pragma unroll
        for (int nt = 0; nt < 4; nt++) {
            int row = nt * 16 + lane_r;
            int off0 = (row * 128 + lane_g * 16) ^ ((row & 7) << 4);
            bf16x8 v0 = *reinterpret_cast<const bf16x8*>((const char*)Vl + off0);
            bf16x8 v1 = *reinterpret_cast<const bf16x8*>((const char*)Vl + (off0 ^ 64));
            oacc[nt] = mfma16(pa0, v0, oacc[nt]);
            oacc[nt] = mfma16(pa1, v1, oacc[nt]);
        }
    }

    // finalize: divide by l, write bf16 (B,S,H)
#pragma unroll
    for (int i = 0; i < 4; i++) l_run[i] = 1.0f / l_run[i];
    size_t robase = (size_t)b * S_ + qt * 64 + w * 16 + lane_g * 4;
#pragma unroll
    for (int nt = 0; nt < 4; nt++)
#pragma unroll
        for (int i = 0; i < 4; i++) {
            float v = oacc[nt][i] * l_run[i];
            ao[(robase + i) * 1024 + h * 64 + nt * 16 + lane_r] = f2bf(v);
        }
}

// ---------------------------------------------------------------------------
extern "C" void kernel_launch(void* const* d_in, const int* in_sizes, int n_in,
                              void* d_out, int out_size, void* d_ws, size_t ws_size,
                              hipStream_t stream)
{
    const float* x  = (const float*)d_in[0];
    const float* wq = (const float*)d_in[1];
    const float* wk = (const float*)d_in[2];
    const float* wv = (const float*)d_in[3];
    const float* wo = (const float*)d_in[4];
    const int* mask = (const int*)d_in[5];

    unsigned short* ws   = (unsigned short*)d_ws;
    unsigned short* xb   = ws;                 // M*K bf16; reused as attn-out
    unsigned short* wqb  = ws + 8388608;
    unsigned short* wkb  = ws + 9437184;
    unsigned short* wvb  = ws + 10485760;
    unsigned short* wob  = ws + 11534336;
    unsigned short* qbuf = ws + 12582912;
    unsigned short* kbuf = ws + 20971520;
    unsigned short* vtb  = ws + 29360128;
    float* cosb = (float*)(ws + 37748736);
    float* sinb = cosb + 65536;
    unsigned short* aob = xb;                  // alias: xb dead after V GEMM

    prep_convert<<<12288, 256, 0, stream>>>(x, wq, wk, wv, wo, ws);
    rope_table<<<256, 256, 0, stream>>>(cosb, sinb);

    dim3 ggrid(8, 64);
    gemm_bt<0><<<ggrid, 256, 0, stream>>>(xb, wqb, qbuf, cosb, sinb, 0.125f);
    gemm_bt<0><<<ggrid, 256, 0, stream>>>(xb, wkb, kbuf, cosb, sinb, 1.0f);
    gemm_bt<1><<<ggrid, 256, 0, stream>>>(xb, wvb, vtb, nullptr, nullptr, 1.0f);

    attn_fwd<<<2048, 256, 0, stream>>>(qbuf, kbuf, vtb, mask, aob);

    gemm_bt<2><<<ggrid, 256, 0, stream>>>(aob, wob, d_out, nullptr, nullptr, 1.0f);
}

// Round 2
// 260.674 us; speedup vs baseline: 1.3062x; 1.3062x over previous
//
#include <hip/hip_runtime.h>
#include <hip/hip_bf16.h>

// Problem constants
#define B_   4
#define S_   2048
#define H_   1024
#define NH_  16
#define HD_  64
#define M_   8192   // B_*S_
#define K_   1024

using bf16x8 = __bf16 __attribute__((ext_vector_type(8)));
using f32x4  = float __attribute__((ext_vector_type(4)));

__device__ inline f32x4 mfma16(bf16x8 a, bf16x8 b, f32x4 c) {
    return __builtin_amdgcn_mfma_f32_16x16x32_bf16(a, b, c, 0, 0, 0);
}

__device__ inline unsigned short f2bf(float f) {
    __hip_bfloat16 h = __float2bfloat16(f);
    return *reinterpret_cast<unsigned short*>(&h);
}

// pack 2 f32 -> 2 bf16 in one u32 (no builtin on gfx950; inline asm per T12)
__device__ inline unsigned cvt_pk_bf16(float lo, float hi) {
    unsigned r;
    asm("v_cvt_pk_bf16_f32 %0, %1, %2" : "=v"(r) : "v"(lo), "v"(hi));
    return r;
}

#define EXP2F(x) __builtin_amdgcn_exp2f(x)

// ---------------------------------------------------------------------------
// Workspace layout (elements of ushort unless noted):
//   xb   @ 0          (M*K)      bf16 x            [also reused as attn-out]
//   wqb  @ 8388608    (1M)
//   wkb  @ 9437184
//   wvb  @ 10485760
//   wob  @ 11534336
//   qbuf @ 12582912   (B,NH,S,HD) bf16, RoPE'd, pre-scaled by 0.125*log2(e)
//   kbuf @ 20971520   (B,NH,S,HD) bf16, RoPE'd
//   vtbuf@ 29360128   (B,NH,HD,S) bf16 (transposed V)
//   cos  @ 37748736 (float, 65536) ; sin follows
// ---------------------------------------------------------------------------

__global__ __launch_bounds__(256) void prep_convert(
    const float* __restrict__ x,  const float* __restrict__ wq,
    const float* __restrict__ wk, const float* __restrict__ wv,
    const float* __restrict__ wo, unsigned short* __restrict__ ws)
{
    size_t u = (size_t)blockIdx.x * 256 + threadIdx.x;   // 3,145,728 units of 4 floats
    const float* src; unsigned short* dst; size_t off;
    if (u < 2097152)      { src = x;  dst = ws;            off = u * 4; }
    else if (u < 2359296) { src = wq; dst = ws + 8388608;  off = (u - 2097152) * 4; }
    else if (u < 2621440) { src = wk; dst = ws + 9437184;  off = (u - 2359296) * 4; }
    else if (u < 2883584) { src = wv; dst = ws + 10485760; off = (u - 2621440) * 4; }
    else                  { src = wo; dst = ws + 11534336; off = (u - 2883584) * 4; }
    float4 v = *reinterpret_cast<const float4*>(src + off);
    ushort4 o;
    o.x = f2bf(v.x); o.y = f2bf(v.y); o.z = f2bf(v.z); o.w = f2bf(v.w);
    *reinterpret_cast<ushort4*>(dst + off) = o;
}

// cos/sin tables: [S][32] each
__global__ __launch_bounds__(256) void rope_table(float* __restrict__ cosb,
                                                  float* __restrict__ sinb)
{
    int idx = blockIdx.x * 256 + threadIdx.x;   // 65536
    int pos = idx >> 5, i = idx & 31;
    float inv = expf(-(float)(2 * i) * (9.210340371976184f / 64.0f));
    float ang = (float)pos * inv;
    cosb[idx] = cosf(ang);
    sinb[idx] = sinf(ang);
}

// ---------------------------------------------------------------------------
// GEMM: C[M x 1024] = A[M x 1024] * W^T   (W stored row-major [1024 x 1024])
// 128x128 block tile, 4 waves of 64x64, BK=64, XOR-swizzled LDS.
// EPI 0: RoPE + scale -> bf16 (B,NH,S,HD)
// EPI 1: transposed V -> bf16 (B,NH,HD,S)
// EPI 2: fp32 -> out (B,S,H)
// ---------------------------------------------------------------------------
template<int EPI>
__global__ __launch_bounds__(256) void gemm_bt(
    const unsigned short* __restrict__ A,
    const unsigned short* __restrict__ W,
    void* __restrict__ outp,
    const float* __restrict__ cosb, const float* __restrict__ sinb,
    float scale)
{
    __shared__ alignas(16) unsigned short Al[128 * 64];
    __shared__ alignas(16) unsigned short Bl[128 * 64];

    const int t = threadIdx.x;
    const int l = t & 63;
    const int w = t >> 6;
    const int lane_r = l & 15, lane_g = l >> 4;
    const int bn = blockIdx.x, bm = blockIdx.y;
    const size_t rowbase = (size_t)bm * 128;
    const int colbase = bn * 128;
    const int wm = (w >> 1) * 64, wn = (w & 1) * 64;
    const int r0 = t >> 3, c8 = t & 7;

    f32x4 zero4 = {0.f, 0.f, 0.f, 0.f};
    f32x4 acc[4][4];
#pragma unroll
    for (int a = 0; a < 4; a++)
#pragma unroll
        for (int b2 = 0; b2 < 4; b2++) acc[a][b2] = zero4;

    for (int k0 = 0; k0 < K_; k0 += 64) {
        bf16x8 ra[4], rb[4];
#pragma unroll
        for (int i = 0; i < 4; i++) {
            int row = i * 32 + r0;
            ra[i] = *reinterpret_cast<const bf16x8*>(A + (rowbase + row) * K_ + k0 + c8 * 8);
            rb[i] = *reinterpret_cast<const bf16x8*>(W + (size_t)(colbase + row) * K_ + k0 + c8 * 8);
        }
        __syncthreads();
#pragma unroll
        for (int i = 0; i < 4; i++) {
            int row = i * 32 + r0;
            int off = (row * 128 + c8 * 16) ^ ((row & 7) << 4);
            *reinterpret_cast<bf16x8*>((char*)Al + off) = ra[i];
            *reinterpret_cast<bf16x8*>((char*)Bl + off) = rb[i];
        }
        __syncthreads();

        bf16x8 af[4][2], bfr[4][2];
#pragma unroll
        for (int mt = 0; mt < 4; mt++)
#pragma unroll
            for (int kk = 0; kk < 2; kk++) {
                int rowa = wm + mt * 16 + lane_r;
                int offa = (rowa * 128 + kk * 64 + lane_g * 16) ^ ((rowa & 7) << 4);
                af[mt][kk] = *reinterpret_cast<const bf16x8*>((const char*)Al + offa);
                int rowb = wn + mt * 16 + lane_r;
                int offb = (rowb * 128 + kk * 64 + lane_g * 16) ^ ((rowb & 7) << 4);
                bfr[mt][kk] = *reinterpret_cast<const bf16x8*>((const char*)Bl + offb);
            }
#pragma unroll
        for (int mt = 0; mt < 4; mt++)
#pragma unroll
            for (int nt = 0; nt < 4; nt++) {
                acc[mt][nt] = mfma16(af[mt][0], bfr[nt][0], acc[mt][nt]);
                acc[mt][nt] = mfma16(af[mt][1], bfr[nt][1], acc[mt][nt]);
            }
    }

    // Epilogue.  D-layout: row = (l>>4)*4 + i, col = l&15 within each 16x16.
#pragma unroll
    for (int mt = 0; mt < 4; mt++) {
#pragma unroll
        for (int nt = 0; nt < 4; nt++) {
            if constexpr (EPI == 2) {
                float* out = (float*)outp;
#pragma unroll
                for (int i = 0; i < 4; i++) {
                    size_t r = rowbase + wm + mt * 16 + lane_g * 4 + i;
                    int n = colbase + wn + nt * 16 + lane_r;
                    out[r * 1024 + n] = acc[mt][nt][i];
                }
            } else if constexpr (EPI == 0) {
                unsigned short* out = (unsigned short*)outp;
#pragma unroll
                for (int i = 0; i < 4; i++) {
                    size_t r = rowbase + wm + mt * 16 + lane_g * 4 + i;
                    int n = colbase + wn + nt * 16 + lane_r;
                    int b   = (int)(r >> 11);
                    int pos = (int)(r & 2047);
                    int h = n >> 6, d = n & 63;
                    float cv = cosb[pos * 32 + (d >> 1)];
                    float sv = sinb[pos * 32 + (d >> 1)];
                    float val = acc[mt][nt][i];
                    float partner = __shfl_xor(val, 1);
                    float o = (d & 1) ? (partner * sv + val * cv)
                                      : (val * cv - partner * sv);
                    o *= scale;
                    out[(((size_t)(b * NH_ + h)) * S_ + pos) * 64 + d] = f2bf(o);
                }
            } else { // EPI == 1 : transposed V
                unsigned short* out = (unsigned short*)outp;
                size_t rr = rowbase + wm + mt * 16 + lane_g * 4;
                int n = colbase + wn + nt * 16 + lane_r;
                int b   = (int)(rr >> 11);
                int pos = (int)(rr & 2047);
                int h = n >> 6, d = n & 63;
                ushort4 o;
                o.x = f2bf(acc[mt][nt][0]); o.y = f2bf(acc[mt][nt][1]);
                o.z = f2bf(acc[mt][nt][2]); o.w = f2bf(acc[mt][nt][3]);
                *reinterpret_cast<ushort4*>(
                    out + (((size_t)(b * NH_ + h)) * 64 + d) * S_ + pos) = o;
            }
        }
    }
}

// ---------------------------------------------------------------------------
// Flash attention, swapped-operand form:
//   S^T = mfma(K, Q)   -> each lane owns ONE q-row (q = lane&15): scalar m/l
//   O^T = mfma(V^T, P^T) -> acc col = q = lane&15, matches softmax stats
// exp2 domain (Q pre-scaled by 0.125*log2e), additive ±inf mask bias,
// defer-max (T13), packed cvt_pk P-writes, K/V register prefetch (T14-lite).
// One (b,h) x 64 q-rows per block, 4 waves x 16 q-rows.
// ---------------------------------------------------------------------------
__global__ __launch_bounds__(256) void attn_fwd(
    const unsigned short* __restrict__ qb, const unsigned short* __restrict__ kb,
    const unsigned short* __restrict__ vt, const int* __restrict__ mask,
    unsigned short* __restrict__ ao)
{
    __shared__ alignas(16) unsigned short Kl[64 * 64];
    __shared__ alignas(16) unsigned short Vl[64 * 64];
    __shared__ alignas(16) unsigned short Pl[4][16 * 64];
    __shared__ alignas(16) float Mb[S_];

    // XCD-clustering swizzle: all 32 q-tiles of a (b,h) land on one XCD.
    const int bid = blockIdx.x;
    const int xcd = bid & 7, idx = bid >> 3;
    const int bh = xcd * 8 + (idx >> 5);
    const int qt = idx & 31;
    const int b = bh >> 4, h = bh & 15;

    const int t = threadIdx.x, l = t & 63, w = t >> 6;
    const int lane_r = l & 15, lane_g = l >> 4;
    const int r0 = t >> 3, c8 = t & 7;

    const unsigned short* qp = qb + (size_t)bh * S_ * 64;
    const unsigned short* kp = kb + (size_t)bh * S_ * 64;
    const unsigned short* vp = vt + (size_t)bh * 64 * S_;

    {   // mask -> additive f32 bias (0 or -inf) in LDS, once
        const int4* msrc = reinterpret_cast<const int4*>(mask + (size_t)b * S_);
        float4* mdst = reinterpret_cast<float4*>(Mb);
        const float NINF = -__builtin_inff();
        for (int i = t; i < S_ / 4; i += 256) {
            int4 mv = msrc[i];
            float4 bv;
            bv.x = mv.x ? 0.f : NINF; bv.y = mv.y ? 0.f : NINF;
            bv.z = mv.z ? 0.f : NINF; bv.w = mv.w ? 0.f : NINF;
            mdst[i] = bv;
        }
    }

    // Q fragments (pre-scaled by 0.125*log2e in projection epilogue)
    bf16x8 qf[2];
    {
        int qrow = qt * 64 + w * 16 + lane_r;
        qf[0] = *reinterpret_cast<const bf16x8*>(qp + (size_t)qrow * 64 + lane_g * 8);
        qf[1] = *reinterpret_cast<const bf16x8*>(qp + (size_t)qrow * 64 + 32 + lane_g * 8);
    }

    f32x4 zero4 = {0.f, 0.f, 0.f, 0.f};
    float m_run = -3.0e38f, l_run = 0.f;
    f32x4 oacc[4];
#pragma unroll
    for (int i = 0; i < 4; i++) oacc[i] = zero4;

    // prefetch kt=0 K/V tiles into registers
    bf16x8 rka[2], rva[2], rkb[2], rvb[2];
#pragma unroll
    for (int i = 0; i < 2; i++) {
        int row = i * 32 + r0;
        rka[i] = *reinterpret_cast<const bf16x8*>(kp + (size_t)row * 64 + c8 * 8);
        rva[i] = *reinterpret_cast<const bf16x8*>(vp + (size_t)row * S_ + c8 * 8);
    }

    for (int kt = 0; kt < 32; kt++) {
        __syncthreads();   // previous tile's compute done; LDS free (also covers Mb)
#pragma unroll
        for (int i = 0; i < 2; i++) {
            int row = i * 32 + r0;
            int off = (row * 128 + c8 * 16) ^ ((row & 7) << 4);
            *reinterpret_cast<bf16x8*>((char*)Kl + off) = rka[i];
            *reinterpret_cast<bf16x8*>((char*)Vl + off) = rva[i];
        }
        if (kt + 1 < 32) {   // issue next tile's global loads under this compute
#pragma unroll
            for (int i = 0; i < 2; i++) {
                int row = i * 32 + r0;
                rkb[i] = *reinterpret_cast<const bf16x8*>(kp + (size_t)((kt + 1) * 64 + row) * 64 + c8 * 8);
                rvb[i] = *reinterpret_cast<const bf16x8*>(vp + (size_t)row * S_ + (kt + 1) * 64 + c8 * 8);
            }
        }
        __syncthreads();   // K/V tile visible

        // S^T = K x Q : s[nt] row = key nt*16+lane_g*4+i, col = q = lane_r
        f32x4 s[4];
#pragma unroll
        for (int nt = 0; nt < 4; nt++) {
            int row = nt * 16 + lane_r;
            int off0 = (row * 128 + lane_g * 16) ^ ((row & 7) << 4);
            bf16x8 k0v = *reinterpret_cast<const bf16x8*>((const char*)Kl + off0);
            bf16x8 k1v = *reinterpret_cast<const bf16x8*>((const char*)Kl + (off0 ^ 64));
            s[nt] = mfma16(k0v, qf[0], zero4);
            s[nt] = mfma16(k1v, qf[1], s[nt]);
        }
        // additive mask bias (float4, broadcast across lane_r -> conflict-free)
#pragma unroll
        for (int nt = 0; nt < 4; nt++) {
            float4 bv = *reinterpret_cast<const float4*>(Mb + kt * 64 + nt * 16 + lane_g * 4);
            s[nt][0] += bv.x; s[nt][1] += bv.y; s[nt][2] += bv.z; s[nt][3] += bv.w;
        }
        // per-lane row max (16 local values + 2 shfls)
        float pmax = fmaxf(fmaxf(s[0][0], s[0][1]), fmaxf(s[0][2], s[0][3]));
#pragma unroll
        for (int nt = 1; nt < 4; nt++)
            pmax = fmaxf(pmax, fmaxf(fmaxf(s[nt][0], s[nt][1]), fmaxf(s[nt][2], s[nt][3])));
        pmax = fmaxf(pmax, __shfl_xor(pmax, 16));
        pmax = fmaxf(pmax, __shfl_xor(pmax, 32));
        // defer-max (T13): only rescale when the running max grew by >8 (log2)
        if (!__all(pmax <= m_run + 8.0f)) {
            float mnew = fmaxf(m_run, pmax);
            float sc = EXP2F(m_run - mnew);
            m_run = mnew;
            l_run *= sc;
#pragma unroll
            for (int nt = 0; nt < 4; nt++)
#pragma unroll
                for (int i = 0; i < 4; i++) oacc[nt][i] *= sc;
        }
        // p = exp2(s - m), per-lane sum
        float rs = 0.f;
        f32x4 p[4];
#pragma unroll
        for (int nt = 0; nt < 4; nt++)
#pragma unroll
            for (int i = 0; i < 4; i++) {
                float pv = EXP2F(s[nt][i] - m_run);
                p[nt][i] = pv;
                rs += pv;
            }
        rs += __shfl_xor(rs, 16);
        rs += __shfl_xor(rs, 32);
        l_run += rs;

        // P^T -> per-wave LDS: packed b64 writes (keys contiguous per lane)
        unsigned short* pl = (unsigned short*)Pl[w];
#pragma unroll
        for (int nt = 0; nt < 4; nt++) {
            uint2 u;
            u.x = cvt_pk_bf16(p[nt][0], p[nt][1]);
            u.y = cvt_pk_bf16(p[nt][2], p[nt][3]);
            int off = (lane_r * 128 + (nt * 16 + lane_g * 4) * 2) ^ ((lane_r & 7) << 4);
            *reinterpret_cast<uint2*>((char*)pl + off) = u;
        }
        asm volatile("" ::: "memory");

        // P^T B-fragments: row q = lane_r, keys lane_g*8.. (+32)
        int pboff = (lane_r * 128 + lane_g * 16) ^ ((lane_r & 7) << 4);
        bf16x8 pb0 = *reinterpret_cast<const bf16x8*>((const char*)pl + pboff);
        bf16x8 pb1 = *reinterpret_cast<const bf16x8*>((const char*)pl + (pboff ^ 64));

        // O^T += V^T x P^T
#pragma unroll
        for (int nt = 0; nt < 4; nt++) {
            int row = nt * 16 + lane_r;
            int off0 = (row * 128 + lane_g * 16) ^ ((row & 7) << 4);
            bf16x8 v0 = *reinterpret_cast<const bf16x8*>((const char*)Vl + off0);
            bf16x8 v1 = *reinterpret_cast<const bf16x8*>((const char*)Vl + (off0 ^ 64));
            oacc[nt] = mfma16(v0, pb0, oacc[nt]);
            oacc[nt] = mfma16(v1, pb1, oacc[nt]);
        }

        // rotate prefetch regs
#pragma unroll
        for (int i = 0; i < 2; i++) { rka[i] = rkb[i]; rva[i] = rvb[i]; }
    }

    // finalize: O^T lane holds d = nt*16+lane_g*4+i for q-row = lane_r (fixed)
    float rl = 1.0f / l_run;
    size_t orow = (size_t)b * S_ + qt * 64 + w * 16 + lane_r;
    unsigned short* aor = ao + orow * 1024 + h * 64;
#pragma unroll
    for (int nt = 0; nt < 4; nt++) {
        ushort4 o;
        o.x = f2bf(oacc[nt][0] * rl); o.y = f2bf(oacc[nt][1] * rl);
        o.z = f2bf(oacc[nt][2] * rl); o.w = f2bf(oacc[nt][3] * rl);
        *reinterpret_cast<ushort4*>(aor + nt * 16 + lane_g * 4) = o;
    }
}

// ---------------------------------------------------------------------------
extern "C" void kernel_launch(void* const* d_in, const int* in_sizes, int n_in,
                              void* d_out, int out_size, void* d_ws, size_t ws_size,
                              hipStream_t stream)
{
    const float* x  = (const float*)d_in[0];
    const float* wq = (const float*)d_in[1];
    const float* wk = (const float*)d_in[2];
    const float* wv = (const float*)d_in[3];
    const float* wo = (const float*)d_in[4];
    const int* mask = (const int*)d_in[5];

    unsigned short* ws   = (unsigned short*)d_ws;
    unsigned short* xb   = ws;                 // M*K bf16; reused as attn-out
    unsigned short* wqb  = ws + 8388608;
    unsigned short* wkb  = ws + 9437184;
    unsigned short* wvb  = ws + 10485760;
    unsigned short* wob  = ws + 11534336;
    unsigned short* qbuf = ws + 12582912;
    unsigned short* kbuf = ws + 20971520;
    unsigned short* vtb  = ws + 29360128;
    float* cosb = (float*)(ws + 37748736);
    float* sinb = cosb + 65536;
    unsigned short* aob = xb;                  // alias: xb dead after V GEMM

    prep_convert<<<12288, 256, 0, stream>>>(x, wq, wk, wv, wo, ws);
    rope_table<<<256, 256, 0, stream>>>(cosb, sinb);

    dim3 ggrid(8, 64);
    // Q scale = (1/sqrt(64)) * log2(e): softmax runs in exp2 domain
    gemm_bt<0><<<ggrid, 256, 0, stream>>>(xb, wqb, qbuf, cosb, sinb, 0.18033688089184827f);
    gemm_bt<0><<<ggrid, 256, 0, stream>>>(xb, wkb, kbuf, cosb, sinb, 1.0f);
    gemm_bt<1><<<ggrid, 256, 0, stream>>>(xb, wvb, vtb, nullptr, nullptr, 1.0f);

    attn_fwd<<<2048, 256, 0, stream>>>(qbuf, kbuf, vtb, mask, aob);

    gemm_bt<2><<<ggrid, 256, 0, stream>>>(aob, wob, d_out, nullptr, nullptr, 1.0f);
}